// Round 2
// baseline (429.411 us; speedup 1.0000x reference)
//
#include <hip/hip_runtime.h>
#include <math.h>

#define B_  16
#define C_  256
#define H_  128
#define W_  128
#define HW  16384       // H_*W_
#define KK  7

// ---------------------------------------------------------------------------
// Kernel 1: channel mean + max over C=256 with 2-way C-split per block.
//   Blocks 0..255 : 512 threads. Waves 0-3 reduce channels [0,128) for 256
//                   float4 positions; waves 4-7 reduce [128,256) for the SAME
//                   positions. LDS combine, then half-0 threads write sf.
//   Block 256     : w2 [98,16,3,3] -> w2r [2,16,3,3] mean-over-49 reduction
//                   (conv linear in weights), folded in to save a launch.
// ---------------------------------------------------------------------------
__global__ __launch_bounds__(512) void k_stage1(const float* __restrict__ x,
                                                const float* __restrict__ w2,
                                                const float* __restrict__ b2,
                                                float* __restrict__ sf,
                                                float* __restrict__ w2r,
                                                float* __restrict__ b2r) {
    if (blockIdx.x == 256) {
        int tid = threadIdx.x;
        if (tid < 288) {
            int c = tid / 144;            // group 0/1 (144 = 16*9)
            int r = tid % 144;
            float s = 0.f;
            for (int j = 0; j < 49; ++j) s += w2[(size_t)(c * 49 + j) * 144 + r];
            w2r[tid] = s * (1.0f / 49.0f);
        } else if (tid < 290) {
            int c = tid - 288;
            float s = 0.f;
            for (int j = 0; j < 49; ++j) s += b2[c * 49 + j];
            b2r[c] = s * (1.0f / 49.0f);
        }
        return;
    }

    __shared__ float4 ls[256];   // partial sums from half 1
    __shared__ float4 lm[256];   // partial maxes from half 1

    int tid  = threadIdx.x;
    int lane = tid & 255;                 // position slot within block
    int half = tid >> 8;                  // 0: channels 0-127, 1: 128-255
    int pos  = blockIdx.x * 256 + lane;   // 0 .. 65535
    int b    = pos >> 12;                 // HW/4 = 4096 float4 per image
    int p    = pos & 4095;

    const float4* xp = (const float4*)x
                     + (size_t)b * (C_ * 4096)
                     + (size_t)(half * 128) * 4096
                     + p;

    float4 s0 = make_float4(0.f, 0.f, 0.f, 0.f), s1 = s0, s2 = s0, s3 = s0;
    const float NI = -3.402823466e+38f;
    float4 m0 = make_float4(NI, NI, NI, NI), m1 = m0, m2 = m0, m3 = m0;

    // 16 iterations x 8 loads in flight; 4 independent accumulator chains.
    for (int c = 0; c < 128; c += 8) {
        float4 v0 = xp[(size_t)(c + 0) * 4096];
        float4 v1 = xp[(size_t)(c + 1) * 4096];
        float4 v2 = xp[(size_t)(c + 2) * 4096];
        float4 v3 = xp[(size_t)(c + 3) * 4096];
        float4 v4 = xp[(size_t)(c + 4) * 4096];
        float4 v5 = xp[(size_t)(c + 5) * 4096];
        float4 v6 = xp[(size_t)(c + 6) * 4096];
        float4 v7 = xp[(size_t)(c + 7) * 4096];

        s0.x += v0.x; s0.y += v0.y; s0.z += v0.z; s0.w += v0.w;
        s1.x += v1.x; s1.y += v1.y; s1.z += v1.z; s1.w += v1.w;
        s2.x += v2.x; s2.y += v2.y; s2.z += v2.z; s2.w += v2.w;
        s3.x += v3.x; s3.y += v3.y; s3.z += v3.z; s3.w += v3.w;
        s0.x += v4.x; s0.y += v4.y; s0.z += v4.z; s0.w += v4.w;
        s1.x += v5.x; s1.y += v5.y; s1.z += v5.z; s1.w += v5.w;
        s2.x += v6.x; s2.y += v6.y; s2.z += v6.z; s2.w += v6.w;
        s3.x += v7.x; s3.y += v7.y; s3.z += v7.z; s3.w += v7.w;

        m0.x = fmaxf(m0.x, v0.x); m0.y = fmaxf(m0.y, v0.y); m0.z = fmaxf(m0.z, v0.z); m0.w = fmaxf(m0.w, v0.w);
        m1.x = fmaxf(m1.x, v1.x); m1.y = fmaxf(m1.y, v1.y); m1.z = fmaxf(m1.z, v1.z); m1.w = fmaxf(m1.w, v1.w);
        m2.x = fmaxf(m2.x, v2.x); m2.y = fmaxf(m2.y, v2.y); m2.z = fmaxf(m2.z, v2.z); m2.w = fmaxf(m2.w, v2.w);
        m3.x = fmaxf(m3.x, v3.x); m3.y = fmaxf(m3.y, v3.y); m3.z = fmaxf(m3.z, v3.z); m3.w = fmaxf(m3.w, v3.w);
        m0.x = fmaxf(m0.x, v4.x); m0.y = fmaxf(m0.y, v4.y); m0.z = fmaxf(m0.z, v4.z); m0.w = fmaxf(m0.w, v4.w);
        m1.x = fmaxf(m1.x, v5.x); m1.y = fmaxf(m1.y, v5.y); m1.z = fmaxf(m1.z, v5.z); m1.w = fmaxf(m1.w, v5.w);
        m2.x = fmaxf(m2.x, v6.x); m2.y = fmaxf(m2.y, v6.y); m2.z = fmaxf(m2.z, v6.z); m2.w = fmaxf(m2.w, v6.w);
        m3.x = fmaxf(m3.x, v7.x); m3.y = fmaxf(m3.y, v7.y); m3.z = fmaxf(m3.z, v7.z); m3.w = fmaxf(m3.w, v7.w);
    }

    float4 s, m;
    s.x = (s0.x + s1.x) + (s2.x + s3.x);
    s.y = (s0.y + s1.y) + (s2.y + s3.y);
    s.z = (s0.z + s1.z) + (s2.z + s3.z);
    s.w = (s0.w + s1.w) + (s2.w + s3.w);
    m.x = fmaxf(fmaxf(m0.x, m1.x), fmaxf(m2.x, m3.x));
    m.y = fmaxf(fmaxf(m0.y, m1.y), fmaxf(m2.y, m3.y));
    m.z = fmaxf(fmaxf(m0.z, m1.z), fmaxf(m2.z, m3.z));
    m.w = fmaxf(fmaxf(m0.w, m1.w), fmaxf(m2.w, m3.w));

    if (half == 1) { ls[lane] = s; lm[lane] = m; }
    __syncthreads();
    if (half == 0) {
        float4 s2_ = ls[lane];
        float4 m2_ = lm[lane];
        const float inv = 1.0f / 256.0f;
        s.x = (s.x + s2_.x) * inv; s.y = (s.y + s2_.y) * inv;
        s.z = (s.z + s2_.z) * inv; s.w = (s.w + s2_.w) * inv;
        m.x = fmaxf(m.x, m2_.x); m.y = fmaxf(m.y, m2_.y);
        m.z = fmaxf(m.z, m2_.z); m.w = fmaxf(m.w, m2_.w);

        float4* o = (float4*)sf;
        o[(size_t)b * 8192 + p]        = s;   // channel 0: avg
        o[(size_t)b * 8192 + 4096 + p] = m;   // channel 1: max
    }
}

// ---------------------------------------------------------------------------
// Kernel 2 (fully fused): offset branch + bilinear sample + 7x7 attn conv
//                         + sigmoid, all in one block per 16x16 output tile.
// The 7x7 conv needs `sampled` on a 22x22 halo region, which depends on
// offsets at those halo positions -> recompute them locally:
//   sampled 22x22 (origin -3)  <- offsets there  <- h1 24x24 (origin -4)
//   <- sf tile 26x26 (origin -5).
// Recomputation is the identical code path as before, so halo values match
// exactly what the neighbor tile would have produced.
// CRITICAL masks: h1 is ZERO outside the image (conv2 zero-pads h1, not a
// conv of padded sf); `sampled` is ZERO outside the image (conv7 zero-pads).
// LDS ~49 KB -> 3 blocks/CU; 1024 blocks over 256 CUs.
// ---------------------------------------------------------------------------
__global__ __launch_bounds__(256) void k_off_attn(const float* __restrict__ sf,
                                                  const float* __restrict__ w1,
                                                  const float* __restrict__ gamma,
                                                  const float* __restrict__ beta,
                                                  const float* __restrict__ mean,
                                                  const float* __restrict__ var,
                                                  const float* __restrict__ w2r,
                                                  const float* __restrict__ b2r,
                                                  const float* __restrict__ aw,
                                                  float* __restrict__ out) {
    __shared__ float sft[2][26][26];
    __shared__ float h1t[16][24][24];
    __shared__ float smp[2][22][22];
    __shared__ float wl1[288], wl2[288], wl4[98];
    __shared__ float sc[16], bi[16], bl[2];

    int tid = threadIdx.x;
    for (int i = tid; i < 288; i += 256) { wl1[i] = w1[i]; wl2[i] = w2r[i]; }
    if (tid < 98) wl4[tid] = aw[tid];
    if (tid < 16) {
        float s = gamma[tid] * rsqrtf(var[tid] + 1e-5f);
        sc[tid] = s;
        bi[tid] = beta[tid] - mean[tid] * s;
    }
    if (tid < 2) bl[tid] = b2r[tid];

    int blk = blockIdx.x;            // b*64 + tile index (8x8 tiles of 16x16)
    int b   = blk >> 6;
    int t8  = blk & 63;
    int ty0 = (t8 >> 3) << 4;
    int tx0 = (t8 & 7) << 4;
    const float* sfb = sf + ((size_t)b << 15);   // b*2*HW

    // stage sf 26x26 tile (origin ty0-5, tx0-5), zero padded
    for (int i = tid; i < 676; i += 256) {
        int ly = i / 26, lx = i % 26;
        int gy = ty0 + ly - 5, gx = tx0 + lx - 5;
        bool ok = (gy >= 0) & (gy < H_) & (gx >= 0) & (gx < W_);
        int gidx = gy * W_ + gx;
        sft[0][ly][lx] = ok ? sfb[gidx]      : 0.f;
        sft[1][ly][lx] = ok ? sfb[HW + gidx] : 0.f;
    }
    __syncthreads();

    // h1 on 24x24 (origin ty0-4, tx0-4): conv3x3(2->16)+BN+ReLU,
    // forced to ZERO outside the image.
    for (int i = tid; i < 576; i += 256) {
        int ly = i / 24, lx = i % 24;
        int gy = ty0 + ly - 4, gx = tx0 + lx - 4;
        bool inside = (gy >= 0) & (gy < H_) & (gx >= 0) & (gx < W_);
        float in[2][9];
#pragma unroll
        for (int c = 0; c < 2; ++c)
#pragma unroll
            for (int kh = 0; kh < 3; ++kh)
#pragma unroll
                for (int kw = 0; kw < 3; ++kw)
                    in[c][kh * 3 + kw] = sft[c][ly + kh][lx + kw];
#pragma unroll
        for (int oc = 0; oc < 16; ++oc) {
            float acc = 0.f;
#pragma unroll
            for (int c = 0; c < 2; ++c)
#pragma unroll
                for (int k = 0; k < 9; ++k)
                    acc += in[c][k] * wl1[oc * 18 + c * 9 + k];
            h1t[oc][ly][lx] = inside ? fmaxf(acc * sc[oc] + bi[oc], 0.f) : 0.f;
        }
    }
    __syncthreads();

    // sampled on 22x22 (origin ty0-3, tx0-3):
    // conv3x3(16->2 reduced)+bias -> tanh*0.5 -> grid -> clip -> bilinear.
    // ZERO outside the image (conv7's zero padding).
    for (int i = tid; i < 484; i += 256) {
        int ly = i / 22, lx = i % 22;
        int h = ty0 + ly - 3, w = tx0 + lx - 3;
        bool inside = (h >= 0) & (h < H_) & (w >= 0) & (w < W_);

        float off0 = bl[0], off1 = bl[1];
#pragma unroll 4
        for (int ci = 0; ci < 16; ++ci) {
#pragma unroll
            for (int kh = 0; kh < 3; ++kh)
#pragma unroll
                for (int kw = 0; kw < 3; ++kw) {
                    float v = h1t[ci][ly + kh][lx + kw];
                    off0 += v * wl2[ci * 9 + kh * 3 + kw];
                    off1 += v * wl2[144 + ci * 9 + kh * 3 + kw];
                }
        }
        off0 = tanhf(off0) * 0.5f;
        off1 = tanhf(off1) * 0.5f;

        float gx = fmaf((float)w, 2.0f / 127.0f, -1.0f) + off0;
        float gy = fmaf((float)h, 2.0f / 127.0f, -1.0f) + off1;
        gx = fminf(fmaxf(gx, -1.0f), 1.0f);
        gy = fminf(fmaxf(gy, -1.0f), 1.0f);

        // unnormalize, align_corners=False: ix = ((gx+1)*W - 1)/2
        float ix = (gx + 1.0f) * 64.0f - 0.5f;
        float iy = (gy + 1.0f) * 64.0f - 0.5f;
        float x0f = floorf(ix), y0f = floorf(iy);
        int x0 = (int)x0f, y0 = (int)y0f;
        int x1 = x0 + 1,  y1 = y0 + 1;
        float wx1 = ix - x0f, wx0 = 1.0f - wx1;
        float wy1 = iy - y0f, wy0 = 1.0f - wy1;

        float o0 = 0.f, o1 = 0.f;
        if (x0 >= 0 && x0 < W_ && y0 >= 0 && y0 < H_) {
            int idx = y0 * W_ + x0; float wt = wx0 * wy0;
            o0 += sfb[idx] * wt; o1 += sfb[HW + idx] * wt;
        }
        if (x1 >= 0 && x1 < W_ && y0 >= 0 && y0 < H_) {
            int idx = y0 * W_ + x1; float wt = wx1 * wy0;
            o0 += sfb[idx] * wt; o1 += sfb[HW + idx] * wt;
        }
        if (x0 >= 0 && x0 < W_ && y1 >= 0 && y1 < H_) {
            int idx = y1 * W_ + x0; float wt = wx0 * wy1;
            o0 += sfb[idx] * wt; o1 += sfb[HW + idx] * wt;
        }
        if (x1 >= 0 && x1 < W_ && y1 >= 0 && y1 < H_) {
            int idx = y1 * W_ + x1; float wt = wx1 * wy1;
            o0 += sfb[idx] * wt; o1 += sfb[HW + idx] * wt;
        }
        smp[0][ly][lx] = inside ? o0 : 0.f;
        smp[1][ly][lx] = inside ? o1 : 0.f;
    }
    __syncthreads();

    // 7x7 conv (2->1) over smp + sigmoid
    int ly = tid >> 4, lx = tid & 15;
    float acc = 0.f;
#pragma unroll
    for (int c = 0; c < 2; ++c)
#pragma unroll
        for (int ky = 0; ky < KK; ++ky)
#pragma unroll
            for (int kx = 0; kx < KK; ++kx)
                acc += smp[c][ly + ky][lx + kx] * wl4[c * 49 + ky * 7 + kx];

    int h = ty0 + ly, w = tx0 + lx;
    out[((size_t)b << 14) + h * W_ + w] = 1.0f / (1.0f + expf(-acc));
}

// ---------------------------------------------------------------------------
extern "C" void kernel_launch(void* const* d_in, const int* in_sizes, int n_in,
                              void* d_out, int out_size, void* d_ws, size_t ws_size,
                              hipStream_t stream) {
    const float* x     = (const float*)d_in[0];
    const float* w1    = (const float*)d_in[1];
    const float* bn_g  = (const float*)d_in[2];
    const float* bn_b  = (const float*)d_in[3];
    const float* bn_m  = (const float*)d_in[4];
    const float* bn_v  = (const float*)d_in[5];
    const float* w2    = (const float*)d_in[6];
    const float* b2    = (const float*)d_in[7];
    const float* aw    = (const float*)d_in[8];
    float* out = (float*)d_out;

    float* ws = (float*)d_ws;
    float* sf  = ws;                        // B*2*HW = 524288 floats (2 MB... 4 MB)
    float* w2r = sf + (size_t)B_ * 2 * HW;  // 288
    float* b2r = w2r + 288;                 // 2

    // block 256 of k_stage1 performs the w2/b2 reduction
    k_stage1<<<257, 512, 0, stream>>>(x, w2, b2, sf, w2r, b2r);
    k_off_attn<<<B_ * 64, 256, 0, stream>>>(sf, w1, bn_g, bn_b, bn_m, bn_v,
                                            w2r, b2r, aw, out);
}

// Round 3
// 405.034 us; speedup vs baseline: 1.0602x; 1.0602x over previous
//
#include <hip/hip_runtime.h>
#include <math.h>

#define B_  16
#define C_  256
#define H_  128
#define W_  128
#define HW  16384       // H_*W_
#define KK  7

// ---------------------------------------------------------------------------
// Kernel 1: channel mean + max over C=256.  x [B,C,H,W] -> sf [B,2,H,W]
// float4 per thread (4 hw positions), 4-channel unroll for MLP.
// BW-bound at ~43 µs floor (268 MB read); round-1 experiment showed extra
// occupancy/ILP changes nothing -> already saturated.
// ---------------------------------------------------------------------------
__global__ __launch_bounds__(256) void k_reduce_c(const float* __restrict__ x,
                                                  float* __restrict__ sf) {
    int t = blockIdx.x * 256 + threadIdx.x;      // 0 .. B*HW/4-1 = 65535
    int b = t >> 12;                             // HW/4 = 4096 float4 per image
    int p = t & 4095;
    const float4* xp = (const float4*)x + (size_t)b * (C_ * 4096) + p;

    float4 s0 = make_float4(0.f, 0.f, 0.f, 0.f), s1 = s0, s2 = s0, s3 = s0;
    const float NI = -3.402823466e+38f;
    float4 m0 = make_float4(NI, NI, NI, NI), m1 = m0, m2 = m0, m3 = m0;

    for (int c = 0; c < C_; c += 4) {
        float4 v0 = xp[(size_t)(c + 0) * 4096];
        float4 v1 = xp[(size_t)(c + 1) * 4096];
        float4 v2 = xp[(size_t)(c + 2) * 4096];
        float4 v3 = xp[(size_t)(c + 3) * 4096];
        s0.x += v0.x; s0.y += v0.y; s0.z += v0.z; s0.w += v0.w;
        s1.x += v1.x; s1.y += v1.y; s1.z += v1.z; s1.w += v1.w;
        s2.x += v2.x; s2.y += v2.y; s2.z += v2.z; s2.w += v2.w;
        s3.x += v3.x; s3.y += v3.y; s3.z += v3.z; s3.w += v3.w;
        m0.x = fmaxf(m0.x, v0.x); m0.y = fmaxf(m0.y, v0.y); m0.z = fmaxf(m0.z, v0.z); m0.w = fmaxf(m0.w, v0.w);
        m1.x = fmaxf(m1.x, v1.x); m1.y = fmaxf(m1.y, v1.y); m1.z = fmaxf(m1.z, v1.z); m1.w = fmaxf(m1.w, v1.w);
        m2.x = fmaxf(m2.x, v2.x); m2.y = fmaxf(m2.y, v2.y); m2.z = fmaxf(m2.z, v2.z); m2.w = fmaxf(m2.w, v2.w);
        m3.x = fmaxf(m3.x, v3.x); m3.y = fmaxf(m3.y, v3.y); m3.z = fmaxf(m3.z, v3.z); m3.w = fmaxf(m3.w, v3.w);
    }
    float4 s, m;
    s.x = (s0.x + s1.x) + (s2.x + s3.x);
    s.y = (s0.y + s1.y) + (s2.y + s3.y);
    s.z = (s0.z + s1.z) + (s2.z + s3.z);
    s.w = (s0.w + s1.w) + (s2.w + s3.w);
    m.x = fmaxf(fmaxf(m0.x, m1.x), fmaxf(m2.x, m3.x));
    m.y = fmaxf(fmaxf(m0.y, m1.y), fmaxf(m2.y, m3.y));
    m.z = fmaxf(fmaxf(m0.z, m1.z), fmaxf(m2.z, m3.z));
    m.w = fmaxf(fmaxf(m0.w, m1.w), fmaxf(m2.w, m3.w));
    const float inv = 1.0f / 256.0f;
    s.x *= inv; s.y *= inv; s.z *= inv; s.w *= inv;

    float4* o = (float4*)sf;
    o[(size_t)b * 8192 + p]        = s;   // channel 0: avg
    o[(size_t)b * 8192 + 4096 + p] = m;   // channel 1: max
}

// ---------------------------------------------------------------------------
// Kernel 2: reduce w2 [98,16,3,3] -> w2r [2,16,3,3] (mean over 49), b2 -> b2r
// (conv is linear in weights: mean over the 49 output channels per group
//  commutes with the convolution)
// ---------------------------------------------------------------------------
__global__ void k_wreduce(const float* __restrict__ w2, const float* __restrict__ b2,
                          float* __restrict__ w2r, float* __restrict__ b2r) {
    int tid = threadIdx.x;            // 320 threads, 1 block
    if (tid < 288) {
        int c = tid / 144;            // group 0/1 (144 = 16*9)
        int r = tid % 144;
        float s = 0.f;
        for (int j = 0; j < 49; ++j) s += w2[(size_t)(c * 49 + j) * 144 + r];
        w2r[tid] = s * (1.0f / 49.0f);
    } else if (tid < 290) {
        int c = tid - 288;
        float s = 0.f;
        for (int j = 0; j < 49; ++j) s += b2[c * 49 + j];
        b2r[c] = s * (1.0f / 49.0f);
    }
}

// ---------------------------------------------------------------------------
// Kernel 3 (fused): conv3x3(2->16)+BN+ReLU -> conv3x3(16->2 reduced)+bias
//                   -> tanh*0.5 -> grid -> clip -> bilinear sample of sf.
// 16x16 output tile per block; sf halo 20x20 and h1 tile 18x18x16 in LDS.
// CRITICAL: h1 is zero OUTSIDE the image (conv2's zero-padding applies to h1,
// not to a conv of zero-padded sf) — mask h1t to 0 at global pos < 0 or >= 128.
// NOTE (round-2 lesson): fusing k4 into this kernel via halo recompute costs
// 1.9x the offset-branch VALU + drops occupancy (49KB LDS) for ~1us of saved
// traffic -> net -17us. Keep k3/k4 separate.
// ---------------------------------------------------------------------------
__global__ __launch_bounds__(256) void k_off_sample(const float* __restrict__ sf,
                                                    const float* __restrict__ w1,
                                                    const float* __restrict__ gamma,
                                                    const float* __restrict__ beta,
                                                    const float* __restrict__ mean,
                                                    const float* __restrict__ var,
                                                    const float* __restrict__ w2r,
                                                    const float* __restrict__ b2r,
                                                    float* __restrict__ sampled) {
    __shared__ float sft[2][20][20];
    __shared__ float h1t[16][18][18];
    __shared__ float wl1[288], wl2[288];
    __shared__ float sc[16], bi[16], bl[2];

    int tid = threadIdx.x;
    for (int i = tid; i < 288; i += 256) { wl1[i] = w1[i]; wl2[i] = w2r[i]; }
    if (tid < 16) {
        float s = gamma[tid] * rsqrtf(var[tid] + 1e-5f);
        sc[tid] = s;
        bi[tid] = beta[tid] - mean[tid] * s;
    }
    if (tid < 2) bl[tid] = b2r[tid];

    int blk = blockIdx.x;            // b*64 + tile index (8x8 tiles of 16x16)
    int b   = blk >> 6;
    int t8  = blk & 63;
    int ty0 = (t8 >> 3) << 4;
    int tx0 = (t8 & 7) << 4;
    const float* sfb = sf + ((size_t)b << 15);   // b*2*HW

    // stage sf halo tile (origin ty0-2, tx0-2), zero padded
    for (int i = tid; i < 400; i += 256) {
        int ly = i / 20, lx = i % 20;
        int gy = ty0 + ly - 2, gx = tx0 + lx - 2;
        bool ok = (gy >= 0) & (gy < H_) & (gx >= 0) & (gx < W_);
        int gidx = gy * W_ + gx;
        sft[0][ly][lx] = ok ? sfb[gidx]      : 0.f;
        sft[1][ly][lx] = ok ? sfb[HW + gidx] : 0.f;
    }
    __syncthreads();

    // h1 on 18x18 (origin ty0-1, tx0-1): conv3x3(2->16)+BN+ReLU,
    // forced to ZERO outside the image (reference pads h1 with zeros)
    for (int i = tid; i < 324; i += 256) {
        int ly = i / 18, lx = i % 18;
        int gy = ty0 + ly - 1, gx = tx0 + lx - 1;
        bool inside = (gy >= 0) & (gy < H_) & (gx >= 0) & (gx < W_);
        float in[2][9];
#pragma unroll
        for (int c = 0; c < 2; ++c)
#pragma unroll
            for (int kh = 0; kh < 3; ++kh)
#pragma unroll
                for (int kw = 0; kw < 3; ++kw)
                    in[c][kh * 3 + kw] = sft[c][ly + kh][lx + kw];
#pragma unroll
        for (int oc = 0; oc < 16; ++oc) {
            float acc = 0.f;
#pragma unroll
            for (int c = 0; c < 2; ++c)
#pragma unroll
                for (int k = 0; k < 9; ++k)
                    acc += in[c][k] * wl1[oc * 18 + c * 9 + k];
            h1t[oc][ly][lx] = inside ? fmaxf(acc * sc[oc] + bi[oc], 0.f) : 0.f;
        }
    }
    __syncthreads();

    // conv3x3(16->2) with 49-mean-reduced weights + tanh*0.5 + grid + sample
    int ly = tid >> 4, lx = tid & 15;
    float off0 = bl[0], off1 = bl[1];
#pragma unroll 4
    for (int ci = 0; ci < 16; ++ci) {
#pragma unroll
        for (int kh = 0; kh < 3; ++kh)
#pragma unroll
            for (int kw = 0; kw < 3; ++kw) {
                float v = h1t[ci][ly + kh][lx + kw];
                off0 += v * wl2[ci * 9 + kh * 3 + kw];
                off1 += v * wl2[144 + ci * 9 + kh * 3 + kw];
            }
    }
    off0 = tanhf(off0) * 0.5f;
    off1 = tanhf(off1) * 0.5f;

    int h = ty0 + ly, w = tx0 + lx;
    float gx = fmaf((float)w, 2.0f / 127.0f, -1.0f) + off0;
    float gy = fmaf((float)h, 2.0f / 127.0f, -1.0f) + off1;
    gx = fminf(fmaxf(gx, -1.0f), 1.0f);
    gy = fminf(fmaxf(gy, -1.0f), 1.0f);

    // unnormalize, align_corners=False: ix = ((gx+1)*W - 1)/2
    float ix = (gx + 1.0f) * 64.0f - 0.5f;
    float iy = (gy + 1.0f) * 64.0f - 0.5f;
    float x0f = floorf(ix), y0f = floorf(iy);
    int x0 = (int)x0f, y0 = (int)y0f;
    int x1 = x0 + 1,  y1 = y0 + 1;
    float wx1 = ix - x0f, wx0 = 1.0f - wx1;
    float wy1 = iy - y0f, wy0 = 1.0f - wy1;

    float o0 = 0.f, o1 = 0.f;
    if (x0 >= 0 && x0 < W_ && y0 >= 0 && y0 < H_) {
        int idx = y0 * W_ + x0; float wt = wx0 * wy0;
        o0 += sfb[idx] * wt; o1 += sfb[HW + idx] * wt;
    }
    if (x1 >= 0 && x1 < W_ && y0 >= 0 && y0 < H_) {
        int idx = y0 * W_ + x1; float wt = wx1 * wy0;
        o0 += sfb[idx] * wt; o1 += sfb[HW + idx] * wt;
    }
    if (x0 >= 0 && x0 < W_ && y1 >= 0 && y1 < H_) {
        int idx = y1 * W_ + x0; float wt = wx0 * wy1;
        o0 += sfb[idx] * wt; o1 += sfb[HW + idx] * wt;
    }
    if (x1 >= 0 && x1 < W_ && y1 >= 0 && y1 < H_) {
        int idx = y1 * W_ + x1; float wt = wx1 * wy1;
        o0 += sfb[idx] * wt; o1 += sfb[HW + idx] * wt;
    }
    int hw = h * W_ + w;
    sampled[((size_t)b << 15) + hw]      = o0;
    sampled[((size_t)b << 15) + HW + hw] = o1;
}

// ---------------------------------------------------------------------------
// Kernel 4: 7x7 conv (2->1, pad 3) + sigmoid, LDS halo tile 22x22x2
// ---------------------------------------------------------------------------
__global__ __launch_bounds__(256) void k_attn(const float* __restrict__ sampled,
                                              const float* __restrict__ aw,
                                              float* __restrict__ out) {
    __shared__ float tile[2][22][22];
    __shared__ float wl[98];
    int tid = threadIdx.x;
    if (tid < 98) wl[tid] = aw[tid];

    int blk = blockIdx.x;            // b*64 + tile index (8x8 tiles of 16x16)
    int b   = blk >> 6;
    int t8  = blk & 63;
    int ty0 = (t8 >> 3) << 4;
    int tx0 = (t8 & 7) << 4;
    const float* sb = sampled + ((size_t)b << 15);

    for (int i = tid; i < 484; i += 256) {
        int ly = i / 22, lx = i % 22;
        int gy = ty0 + ly - 3, gx = tx0 + lx - 3;
        bool ok = (gy >= 0) & (gy < H_) & (gx >= 0) & (gx < W_);
        int gidx = gy * W_ + gx;
        tile[0][ly][lx] = ok ? sb[gidx]      : 0.f;
        tile[1][ly][lx] = ok ? sb[HW + gidx] : 0.f;
    }
    __syncthreads();

    int ly = tid >> 4, lx = tid & 15;
    float acc = 0.f;
#pragma unroll
    for (int c = 0; c < 2; ++c)
#pragma unroll
        for (int ky = 0; ky < KK; ++ky)
#pragma unroll
            for (int kx = 0; kx < KK; ++kx)
                acc += tile[c][ly + ky][lx + kx] * wl[c * 49 + ky * 7 + kx];

    int h = ty0 + ly, w = tx0 + lx;
    out[((size_t)b << 14) + h * W_ + w] = 1.0f / (1.0f + expf(-acc));
}

// ---------------------------------------------------------------------------
extern "C" void kernel_launch(void* const* d_in, const int* in_sizes, int n_in,
                              void* d_out, int out_size, void* d_ws, size_t ws_size,
                              hipStream_t stream) {
    const float* x     = (const float*)d_in[0];
    const float* w1    = (const float*)d_in[1];
    const float* bn_g  = (const float*)d_in[2];
    const float* bn_b  = (const float*)d_in[3];
    const float* bn_m  = (const float*)d_in[4];
    const float* bn_v  = (const float*)d_in[5];
    const float* w2    = (const float*)d_in[6];
    const float* b2    = (const float*)d_in[7];
    const float* aw    = (const float*)d_in[8];
    float* out = (float*)d_out;

    float* ws = (float*)d_ws;
    float* sf      = ws;                            // B*2*HW = 524288 floats
    float* sampled = sf + (size_t)B_ * 2 * HW;      // B*2*HW
    float* w2r     = sampled + (size_t)B_ * 2 * HW; // 288
    float* b2r     = w2r + 288;                     // 2
    // total ws: ~4.2 MB

    k_reduce_c<<<B_ * HW / 4 / 256, 256, 0, stream>>>(x, sf);
    k_wreduce<<<1, 320, 0, stream>>>(w2, b2, w2r, b2r);
    k_off_sample<<<B_ * 64, 256, 0, stream>>>(sf, w1, bn_g, bn_b, bn_m, bn_v,
                                              w2r, b2r, sampled);
    k_attn<<<B_ * 64, 256, 0, stream>>>(sampled, aw, out);
}